// Round 1
// baseline (215.733 us; speedup 1.0000x reference)
//
#include <hip/hip_runtime.h>
#include <hip/hip_bf16.h>

#define SEQ 2048
#define NTOK 4096
#define DIMK 1024

typedef __attribute__((ext_vector_type(8))) short bf16x8;
typedef __attribute__((ext_vector_type(4))) float f32x4;

__device__ inline short f2bf(float f) {
    __hip_bfloat16 h = __float2bfloat16(f);
    return __builtin_bit_cast(short, h);
}

// ---------------- cast fp32 -> bf16 ----------------
__global__ __launch_bounds__(256) void cast_kernel(const float* __restrict__ in,
                                                   short* __restrict__ out, int n4) {
    int i = blockIdx.x * blockDim.x + threadIdx.x;
    if (i < n4) {
        float4 v = reinterpret_cast<const float4*>(in)[i];
        short4 o;
        o.x = f2bf(v.x); o.y = f2bf(v.y); o.z = f2bf(v.z); o.w = f2bf(v.w);
        reinterpret_cast<short4*>(out)[i] = o;
    }
}

// ---------------- GEMM1: qkv = xb @ wb^T, scatter to q/k/vt ----------------
// A [4096][1024] bf16, B [3072][1024] bf16. 128x128 block tile, BK=32, 4 waves (2x2).
__global__ __launch_bounds__(256) void gemm_qkv(const short* __restrict__ xb,
                                                const short* __restrict__ wb,
                                                short* __restrict__ q,
                                                short* __restrict__ k,
                                                short* __restrict__ vt) {
    __shared__ short Al[128][40];
    __shared__ short Bl[128][40];
    int tid = threadIdx.x;
    int m0 = blockIdx.x * 128;
    int n0 = blockIdx.y * 128;
    int w = tid >> 6, lane = tid & 63, lo = lane & 15, hi = lane >> 4;
    int wm = (w >> 1) * 64, wn = (w & 1) * 64;

    f32x4 acc[4][4];
    for (int a = 0; a < 4; a++)
        for (int b = 0; b < 4; b++)
            for (int r = 0; r < 4; r++) acc[a][b][r] = 0.f;

    for (int k0 = 0; k0 < DIMK; k0 += 32) {
        for (int it = 0; it < 2; ++it) {
            int chunk = it * 256 + tid;
            int row = chunk >> 2;
            int colc = (chunk & 3) * 8;
            *reinterpret_cast<bf16x8*>(&Al[row][colc]) =
                *reinterpret_cast<const bf16x8*>(xb + (size_t)(m0 + row) * DIMK + k0 + colc);
            *reinterpret_cast<bf16x8*>(&Bl[row][colc]) =
                *reinterpret_cast<const bf16x8*>(wb + (size_t)(n0 + row) * DIMK + k0 + colc);
        }
        __syncthreads();
        bf16x8 af[4], bfr[4];
        for (int mt = 0; mt < 4; mt++)
            af[mt] = *reinterpret_cast<const bf16x8*>(&Al[wm + mt * 16 + lo][hi * 8]);
        for (int nt = 0; nt < 4; nt++)
            bfr[nt] = *reinterpret_cast<const bf16x8*>(&Bl[wn + nt * 16 + lo][hi * 8]);
        for (int mt = 0; mt < 4; mt++)
            for (int nt = 0; nt < 4; nt++)
                acc[mt][nt] = __builtin_amdgcn_mfma_f32_16x16x32_bf16(af[mt], bfr[nt],
                                                                      acc[mt][nt], 0, 0, 0);
        __syncthreads();
    }

    // epilogue: C row = m0+wm+mt*16+hi*4+r (token), col = n0+wn+nt*16+lo (e)
    for (int mt = 0; mt < 4; mt++) {
        int trow = m0 + wm + mt * 16 + hi * 4;
        for (int nt = 0; nt < 4; nt++) {
            int e = n0 + wn + nt * 16 + lo;
            for (int r = 0; r < 4; r++) {
                float val = acc[mt][nt][r];
                int t = trow + r;
                int b = t >> 11, nn = t & 2047;
                if (e < 1024) {
                    int h = e >> 6, dh = e & 63;
                    q[((size_t)(b * 16 + h) * SEQ + nn) * 64 + dh] = f2bf(val * 0.125f);
                } else if (e < 2048) {
                    int e2 = e - 1024; int h = e2 >> 6, dh = e2 & 63;
                    k[((size_t)(b * 16 + h) * SEQ + nn) * 64 + dh] = f2bf(val);
                } else {
                    int e2 = e - 2048; int h = e2 >> 6, dh = e2 & 63;
                    vt[((size_t)(b * 16 + h) * 64 + dh) * SEQ + nn] = f2bf(val);
                }
            }
        }
    }
}

// ---------------- flash attention ----------------
// grid (qtile=32, bh=32), 256 threads = 4 waves; wave w owns 16 q-rows.
__global__ __launch_bounds__(256) void attn_kernel(const short* __restrict__ q,
                                                   const short* __restrict__ k,
                                                   const short* __restrict__ vt,
                                                   short* __restrict__ ao) {
    __shared__ short Kl[64][72];
    __shared__ short Vl[64][72];
    __shared__ short Pl[4][16][72];
    int tid = threadIdx.x;
    int w = tid >> 6, lane = tid & 63, lo = lane & 15, hi = lane >> 4;
    int bh = blockIdx.y;
    int q0 = blockIdx.x * 64 + w * 16;

    const short* qb = q + (size_t)bh * SEQ * 64;
    const short* kb = k + (size_t)bh * SEQ * 64;
    const short* vb = vt + (size_t)bh * 64 * SEQ;

    bf16x8 qf[2];
    for (int j = 0; j < 2; j++)
        qf[j] = *reinterpret_cast<const bf16x8*>(qb + (size_t)(q0 + lo) * 64 + j * 32 + hi * 8);

    float mrun[4], lrun[4];
    f32x4 o[4];
    for (int r = 0; r < 4; r++) { mrun[r] = -__builtin_inff(); lrun[r] = 0.f; }
    for (int d = 0; d < 4; d++)
        for (int r = 0; r < 4; r++) o[d][r] = 0.f;

    for (int kt = 0; kt < SEQ; kt += 64) {
        // stage K tile [64 n][64 d] and Vt tile [64 d][64 n]
        for (int it = 0; it < 2; ++it) {
            int chunk = it * 256 + tid;
            int row = chunk >> 3, colc = (chunk & 7) * 8;
            *reinterpret_cast<bf16x8*>(&Kl[row][colc]) =
                *reinterpret_cast<const bf16x8*>(kb + (size_t)(kt + row) * 64 + colc);
            *reinterpret_cast<bf16x8*>(&Vl[row][colc]) =
                *reinterpret_cast<const bf16x8*>(vb + (size_t)row * SEQ + kt + colc);
        }
        __syncthreads();

        // S = Q K^T  (16 q x 64 k)
        f32x4 s[4];
        for (int sub = 0; sub < 4; sub++)
            for (int r = 0; r < 4; r++) s[sub][r] = 0.f;
        for (int sub = 0; sub < 4; sub++)
            for (int j = 0; j < 2; j++) {
                bf16x8 kf = *reinterpret_cast<const bf16x8*>(&Kl[sub * 16 + lo][j * 32 + hi * 8]);
                s[sub] = __builtin_amdgcn_mfma_f32_16x16x32_bf16(qf[j], kf, s[sub], 0, 0, 0);
            }

        // online softmax; rows handled per reg r (q-row = hi*4+r)
        for (int r = 0; r < 4; r++) {
            float mt = fmaxf(fmaxf(s[0][r], s[1][r]), fmaxf(s[2][r], s[3][r]));
            for (int d = 1; d < 16; d <<= 1) mt = fmaxf(mt, __shfl_xor(mt, d));
            float mn = fmaxf(mrun[r], mt);
            float alpha = __expf(mrun[r] - mn);
            mrun[r] = mn;
            float pv[4], rs = 0.f;
            for (int sub = 0; sub < 4; sub++) {
                float p = __expf(s[sub][r] - mn);
                pv[sub] = p; rs += p;
            }
            for (int d = 1; d < 16; d <<= 1) rs += __shfl_xor(rs, d);
            lrun[r] = alpha * lrun[r] + rs;
            for (int ds = 0; ds < 4; ds++) o[ds][r] *= alpha;
            for (int sub = 0; sub < 4; sub++)
                Pl[w][hi * 4 + r][sub * 16 + lo] = f2bf(pv[sub]);
        }
        __syncthreads();  // cross-lane P visibility

        // PV: o[16 q][64 d] += P[16][64] @ V[64][64]
        bf16x8 pa[2];
        for (int j = 0; j < 2; j++)
            pa[j] = *reinterpret_cast<const bf16x8*>(&Pl[w][lo][j * 32 + hi * 8]);
        for (int ds = 0; ds < 4; ds++)
            for (int j = 0; j < 2; j++) {
                bf16x8 vf = *reinterpret_cast<const bf16x8*>(&Vl[ds * 16 + lo][j * 32 + hi * 8]);
                o[ds] = __builtin_amdgcn_mfma_f32_16x16x32_bf16(pa[j], vf, o[ds], 0, 0, 0);
            }
        __syncthreads();  // before restaging K/V
    }

    // epilogue: ao[t][h*64+d] bf16
    int b = bh >> 4, h = bh & 15;
    for (int r = 0; r < 4; r++) {
        int nn = blockIdx.x * 64 + w * 16 + hi * 4 + r;
        int t = b * SEQ + nn;
        float inv = 1.f / lrun[r];
        for (int ds = 0; ds < 4; ds++)
            ao[(size_t)t * 1024 + h * 64 + ds * 16 + lo] = f2bf(o[ds][r] * inv);
    }
}

// ---------------- GEMM2: out = ao @ wob^T (fp32 out) ----------------
__global__ __launch_bounds__(256) void gemm_out(const short* __restrict__ a,
                                                const short* __restrict__ b,
                                                float* __restrict__ out) {
    __shared__ short Al[128][40];
    __shared__ short Bl[128][40];
    int tid = threadIdx.x;
    int m0 = blockIdx.x * 128;
    int n0 = blockIdx.y * 128;
    int w = tid >> 6, lane = tid & 63, lo = lane & 15, hi = lane >> 4;
    int wm = (w >> 1) * 64, wn = (w & 1) * 64;

    f32x4 acc[4][4];
    for (int aa = 0; aa < 4; aa++)
        for (int bb = 0; bb < 4; bb++)
            for (int r = 0; r < 4; r++) acc[aa][bb][r] = 0.f;

    for (int k0 = 0; k0 < DIMK; k0 += 32) {
        for (int it = 0; it < 2; ++it) {
            int chunk = it * 256 + tid;
            int row = chunk >> 2;
            int colc = (chunk & 3) * 8;
            *reinterpret_cast<bf16x8*>(&Al[row][colc]) =
                *reinterpret_cast<const bf16x8*>(a + (size_t)(m0 + row) * DIMK + k0 + colc);
            *reinterpret_cast<bf16x8*>(&Bl[row][colc]) =
                *reinterpret_cast<const bf16x8*>(b + (size_t)(n0 + row) * DIMK + k0 + colc);
        }
        __syncthreads();
        bf16x8 af[4], bfr[4];
        for (int mt = 0; mt < 4; mt++)
            af[mt] = *reinterpret_cast<const bf16x8*>(&Al[wm + mt * 16 + lo][hi * 8]);
        for (int nt = 0; nt < 4; nt++)
            bfr[nt] = *reinterpret_cast<const bf16x8*>(&Bl[wn + nt * 16 + lo][hi * 8]);
        for (int mt = 0; mt < 4; mt++)
            for (int nt = 0; nt < 4; nt++)
                acc[mt][nt] = __builtin_amdgcn_mfma_f32_16x16x32_bf16(af[mt], bfr[nt],
                                                                      acc[mt][nt], 0, 0, 0);
        __syncthreads();
    }

    for (int mt = 0; mt < 4; mt++) {
        int trow = m0 + wm + mt * 16 + hi * 4;
        for (int nt = 0; nt < 4; nt++) {
            int e = n0 + wn + nt * 16 + lo;
            for (int r = 0; r < 4; r++)
                out[(size_t)(trow + r) * 1024 + e] = acc[mt][nt][r];
        }
    }
}

extern "C" void kernel_launch(void* const* d_in, const int* in_sizes, int n_in,
                              void* d_out, int out_size, void* d_ws, size_t ws_size,
                              hipStream_t stream) {
    const float* x = (const float*)d_in[0];
    const float* wqkv = (const float*)d_in[1];
    const float* wout = (const float*)d_in[2];
    float* out = (float*)d_out;

    char* ws = (char*)d_ws;
    short* xb  = (short*)(ws);                       // 8 MB  [4096][1024]
    short* wqb = (short*)(ws + 8388608);             // 6 MB  [3072][1024]
    short* wob = (short*)(ws + 8388608 + 6291456);   // 2 MB  [1024][1024]
    short* qq  = (short*)(ws + 16777216);            // 8 MB  [32][2048][64]
    short* kk  = (short*)(ws + 25165824);            // 8 MB  [32][2048][64]
    short* vt  = (short*)(ws + 33554432);            // 8 MB  [32][64][2048]
    short* ao  = xb;                                 // reuse xb region after GEMM1

    hipLaunchKernelGGL(cast_kernel, dim3(4096), dim3(256), 0, stream, x, xb, 1048576);
    hipLaunchKernelGGL(cast_kernel, dim3(3072), dim3(256), 0, stream, wqkv, wqb, 786432);
    hipLaunchKernelGGL(cast_kernel, dim3(1024), dim3(256), 0, stream, wout, wob, 262144);
    hipLaunchKernelGGL(gemm_qkv, dim3(32, 24), dim3(256), 0, stream, xb, wqb, qq, kk, vt);
    hipLaunchKernelGGL(attn_kernel, dim3(32, 32), dim3(256), 0, stream, qq, kk, vt, ao);
    hipLaunchKernelGGL(gemm_out, dim3(32, 8), dim3(256), 0, stream, ao, wob, out);
}

// Round 2
// 159.265 us; speedup vs baseline: 1.3546x; 1.3546x over previous
//
#include <hip/hip_runtime.h>
#include <hip/hip_bf16.h>

#define SEQ 2048
#define NTOK 4096
#define DIMK 1024

typedef __attribute__((ext_vector_type(8))) short bf16x8;
typedef __attribute__((ext_vector_type(4))) float f32x4;

__device__ inline short f2bf(float f) {
    __hip_bfloat16 h = __float2bfloat16(f);
    return __builtin_bit_cast(short, h);
}

__device__ inline unsigned pack2bf(float a, float b) {
    unsigned ha = (unsigned short)f2bf(a);
    unsigned hb = (unsigned short)f2bf(b);
    return ha | (hb << 16);
}

__device__ inline void gload16(const void* src, void* lds) {
    __builtin_amdgcn_global_load_lds(
        (const __attribute__((address_space(1))) unsigned int*)src,
        (__attribute__((address_space(3))) unsigned int*)lds, 16, 0, 0);
}

// ---------------- cast fp32 -> bf16 ----------------
__global__ __launch_bounds__(256) void cast_kernel(const float* __restrict__ in,
                                                   short* __restrict__ out, int n4) {
    int i = blockIdx.x * blockDim.x + threadIdx.x;
    if (i < n4) {
        float4 v = reinterpret_cast<const float4*>(in)[i];
        short4 o;
        o.x = f2bf(v.x); o.y = f2bf(v.y); o.z = f2bf(v.z); o.w = f2bf(v.w);
        reinterpret_cast<short4*>(out)[i] = o;
    }
}

// ---------------- GEMM1: qkv = xb @ wb^T, scatter to q/k/vt ----------------
// m97 structure: 128x128 tile, BK=32, global_load_lds width-16, linear LDS.
__global__ __launch_bounds__(256) void gemm_qkv(const short* __restrict__ xb,
                                                const short* __restrict__ wb,
                                                short* __restrict__ q,
                                                short* __restrict__ k,
                                                short* __restrict__ vt) {
    __shared__ short Al[128][32];
    __shared__ short Bl[128][32];
    int tid = threadIdx.x;
    int m0 = blockIdx.x * 128;
    int n0 = blockIdx.y * 128;
    int w = tid >> 6, lane = tid & 63, lo = lane & 15, hi = lane >> 4;
    int wm = (w >> 1) * 64, wn = (w & 1) * 64;

    f32x4 acc[4][4];
    for (int a = 0; a < 4; a++)
        for (int b = 0; b < 4; b++)
            for (int r = 0; r < 4; r++) acc[a][b][r] = 0.f;

    int srow = tid >> 2, scol = (tid & 3) * 8;        // round 0 slot
    int srow1 = (tid + 256) >> 2, scol1 = ((tid + 256) & 3) * 8;

    for (int k0 = 0; k0 < DIMK; k0 += 32) {
        gload16(xb + (size_t)(m0 + srow) * DIMK + k0 + scol, (short*)Al + (w * 64) * 8);
        gload16(xb + (size_t)(m0 + srow1) * DIMK + k0 + scol1, (short*)Al + (256 + w * 64) * 8);
        gload16(wb + (size_t)(n0 + srow) * DIMK + k0 + scol, (short*)Bl + (w * 64) * 8);
        gload16(wb + (size_t)(n0 + srow1) * DIMK + k0 + scol1, (short*)Bl + (256 + w * 64) * 8);
        __syncthreads();
        bf16x8 af[4], bfr[4];
        for (int mt = 0; mt < 4; mt++)
            af[mt] = *reinterpret_cast<const bf16x8*>(&Al[wm + mt * 16 + lo][hi * 8]);
        for (int nt = 0; nt < 4; nt++)
            bfr[nt] = *reinterpret_cast<const bf16x8*>(&Bl[wn + nt * 16 + lo][hi * 8]);
        for (int mt = 0; mt < 4; mt++)
            for (int nt = 0; nt < 4; nt++)
                acc[mt][nt] = __builtin_amdgcn_mfma_f32_16x16x32_bf16(af[mt], bfr[nt],
                                                                      acc[mt][nt], 0, 0, 0);
        __syncthreads();
    }

    for (int mt = 0; mt < 4; mt++) {
        int trow = m0 + wm + mt * 16 + hi * 4;
        for (int nt = 0; nt < 4; nt++) {
            int e = n0 + wn + nt * 16 + lo;
            for (int r = 0; r < 4; r++) {
                float val = acc[mt][nt][r];
                int t = trow + r;
                int b = t >> 11, nn = t & 2047;
                if (e < 1024) {
                    int h = e >> 6, dh = e & 63;
                    q[((size_t)(b * 16 + h) * SEQ + nn) * 64 + dh] = f2bf(val * 0.125f);
                } else if (e < 2048) {
                    int e2 = e - 1024; int h = e2 >> 6, dh = e2 & 63;
                    k[((size_t)(b * 16 + h) * SEQ + nn) * 64 + dh] = f2bf(val);
                } else {
                    int e2 = e - 2048; int h = e2 >> 6, dh = e2 & 63;
                    vt[((size_t)(b * 16 + h) * 64 + dh) * SEQ + nn] = f2bf(val);
                }
            }
        }
    }
}

// ---------------- flash attention (swapped QK^T, P in registers) ----------------
// grid (32 qtiles, 32 bh), 4 waves x 16 q-rows. K/V double-buffered in LDS via
// global_load_lds, XOR-swizzled 16B chunks (c' = c ^ (row&7)).
__global__ __launch_bounds__(256) void attn_kernel(const short* __restrict__ q,
                                                   const short* __restrict__ k,
                                                   const short* __restrict__ vt,
                                                   short* __restrict__ ao) {
    __shared__ short Kl[2][64][64];
    __shared__ short Vl[2][64][64];
    int tid = threadIdx.x;
    int w = tid >> 6, lane = tid & 63, lo = lane & 15, hi = lane >> 4;
    int bh = blockIdx.y;
    int q0 = blockIdx.x * 64 + w * 16;

    const short* qb = q + (size_t)bh * SEQ * 64;
    const short* kb = k + (size_t)bh * SEQ * 64;
    const short* vb = vt + (size_t)bh * 64 * SEQ;

    // Q fragment (B-operand): lane holds Q[q0+lo][j*32 + hi*8 ..]
    bf16x8 qf[2];
    for (int j = 0; j < 2; j++)
        qf[j] = *reinterpret_cast<const bf16x8*>(qb + (size_t)(q0 + lo) * 64 + j * 32 + hi * 8);

    // staging slot (per-lane src; dest is wave-uniform base + lane*16)
    int s0row = tid >> 3, s0m = tid & 7;
    int s1row = (tid + 256) >> 3, s1m = (tid + 256) & 7;
    const short* ksrc0 = kb + (size_t)s0row * 64 + ((s0m ^ (s0row & 7)) << 3);
    const short* ksrc1 = kb + (size_t)s1row * 64 + ((s1m ^ (s1row & 7)) << 3);
    const short* vsrc0 = vb + (size_t)s0row * SEQ + ((s0m ^ (s0row & 7)) << 3);
    const short* vsrc1 = vb + (size_t)s1row * SEQ + ((s1m ^ (s1row & 7)) << 3);

    float mrun = -__builtin_inff(), lrun = 0.f;
    f32x4 o[4];
    for (int d = 0; d < 4; d++)
        for (int r = 0; r < 4; r++) o[d][r] = 0.f;

    // prologue: stage tile 0 into buf 0
    {
        gload16(ksrc0, (short*)&Kl[0][0][0] + (w * 64) * 8);
        gload16(ksrc1, (short*)&Kl[0][0][0] + (256 + w * 64) * 8);
        gload16(vsrc0, (short*)&Vl[0][0][0] + (w * 64) * 8);
        gload16(vsrc1, (short*)&Vl[0][0][0] + (256 + w * 64) * 8);
    }
    __syncthreads();

    int cur = 0;
    for (int t = 0; t < SEQ / 64; ++t) {
        // issue next-tile staging into the other buffer
        if (t + 1 < SEQ / 64) {
            int kt = (t + 1) * 64;
            gload16(ksrc0 + kt * 64, (short*)&Kl[cur ^ 1][0][0] + (w * 64) * 8);
            gload16(ksrc1 + kt * 64, (short*)&Kl[cur ^ 1][0][0] + (256 + w * 64) * 8);
            gload16(vsrc0 + kt, (short*)&Vl[cur ^ 1][0][0] + (w * 64) * 8);
            gload16(vsrc1 + kt, (short*)&Vl[cur ^ 1][0][0] + (256 + w * 64) * 8);
        }

        // S^T = K Q^T : lane holds S[q=lo][k = sub*16 + hi*4 + r]
        f32x4 s[4];
        #pragma unroll
        for (int sub = 0; sub < 4; ++sub) {
            int row = sub * 16 + lo;
            const short* kp = &Kl[cur][row][0];
            bf16x8 kf0 = *reinterpret_cast<const bf16x8*>(kp + ((hi ^ (row & 7)) << 3));
            bf16x8 kf1 = *reinterpret_cast<const bf16x8*>(kp + (((4 + hi) ^ (row & 7)) << 3));
            f32x4 z = {0.f, 0.f, 0.f, 0.f};
            z = __builtin_amdgcn_mfma_f32_16x16x32_bf16(kf0, qf[0], z, 0, 0, 0);
            z = __builtin_amdgcn_mfma_f32_16x16x32_bf16(kf1, qf[1], z, 0, 0, 0);
            s[sub] = z;
        }

        // per-lane online softmax (q = lo); reduce across the 4 hi-groups
        float pmax = s[0][0];
        #pragma unroll
        for (int sub = 0; sub < 4; ++sub)
            #pragma unroll
            for (int r = 0; r < 4; ++r) pmax = fmaxf(pmax, s[sub][r]);
        pmax = fmaxf(pmax, __shfl_xor(pmax, 16, 64));
        pmax = fmaxf(pmax, __shfl_xor(pmax, 32, 64));
        float mn = fmaxf(mrun, pmax);
        float alpha = __expf(mrun - mn);
        mrun = mn;
        float p[4][4];
        float rs = 0.f;
        #pragma unroll
        for (int sub = 0; sub < 4; ++sub)
            #pragma unroll
            for (int r = 0; r < 4; ++r) {
                float pe = __expf(s[sub][r] - mn);
                p[sub][r] = pe; rs += pe;
            }
        rs += __shfl_xor(rs, 16, 64);
        rs += __shfl_xor(rs, 32, 64);
        lrun = alpha * lrun + rs;
        #pragma unroll
        for (int ds = 0; ds < 4; ++ds)
            #pragma unroll
            for (int r = 0; r < 4; ++r) o[ds][r] *= alpha;

        // pack P to bf16 pairs: pk[sub][half] = P[k=sub*16+hi*4+2*half+(0,1)][q=lo]
        unsigned pk[4][2];
        #pragma unroll
        for (int sub = 0; sub < 4; ++sub) {
            pk[sub][0] = pack2bf(p[sub][0], p[sub][1]);
            pk[sub][1] = pack2bf(p[sub][2], p[sub][3]);
        }

        // PV: O^T[d][q] += Vt[d][k] * P[q][k]
        #pragma unroll
        for (int koff = 0; koff < 2; ++koff) {
            // build B-frag: lane needs P[q=lo][k = koff*32 + hi*8 + 2m + (0,1)]
            int pbw[4];
            #pragma unroll
            for (int m = 0; m < 4; ++m) {
                int srcl = ((2 * (hi & 1) + (m >> 1)) << 4) | lo;
                int va = __shfl((int)pk[2 * koff + 0][m & 1], srcl, 64);
                int vb2 = __shfl((int)pk[2 * koff + 1][m & 1], srcl, 64);
                pbw[m] = (hi & 2) ? vb2 : va;
            }
            int4 pbi; pbi.x = pbw[0]; pbi.y = pbw[1]; pbi.z = pbw[2]; pbi.w = pbw[3];
            bf16x8 pb = __builtin_bit_cast(bf16x8, pbi);
            #pragma unroll
            for (int ds = 0; ds < 4; ++ds) {
                int row = ds * 16 + lo;
                bf16x8 vfr = *reinterpret_cast<const bf16x8*>(
                    &Vl[cur][row][0] + (((koff * 4 + hi) ^ (row & 7)) << 3));
                o[ds] = __builtin_amdgcn_mfma_f32_16x16x32_bf16(vfr, pb, o[ds], 0, 0, 0);
            }
        }

        __syncthreads();   // drains vmcnt(0): next tile staged; all reads of cur done
        cur ^= 1;
    }

    // epilogue: lane holds O[q=lo][d = ds*16 + hi*4 + r]
    int b = bh >> 4, h = bh & 15;
    int nn = blockIdx.x * 64 + w * 16 + lo;
    size_t tbase = ((size_t)(b * SEQ + nn)) * 1024 + h * 64;
    float inv = 1.f / lrun;
    #pragma unroll
    for (int ds = 0; ds < 4; ++ds) {
        short4 st;
        st.x = f2bf(o[ds][0] * inv);
        st.y = f2bf(o[ds][1] * inv);
        st.z = f2bf(o[ds][2] * inv);
        st.w = f2bf(o[ds][3] * inv);
        *reinterpret_cast<short4*>(&ao[tbase + ds * 16 + hi * 4]) = st;
    }
}

// ---------------- GEMM2: out = ao @ wob^T (fp32 out) ----------------
__global__ __launch_bounds__(256) void gemm_out(const short* __restrict__ a,
                                                const short* __restrict__ b,
                                                float* __restrict__ out) {
    __shared__ short Al[128][32];
    __shared__ short Bl[128][32];
    int tid = threadIdx.x;
    int m0 = blockIdx.x * 128;
    int n0 = blockIdx.y * 128;
    int w = tid >> 6, lane = tid & 63, lo = lane & 15, hi = lane >> 4;
    int wm = (w >> 1) * 64, wn = (w & 1) * 64;

    f32x4 acc[4][4];
    for (int aa = 0; aa < 4; aa++)
        for (int bb = 0; bb < 4; bb++)
            for (int r = 0; r < 4; r++) acc[aa][bb][r] = 0.f;

    int srow = tid >> 2, scol = (tid & 3) * 8;
    int srow1 = (tid + 256) >> 2, scol1 = ((tid + 256) & 3) * 8;

    for (int k0 = 0; k0 < DIMK; k0 += 32) {
        gload16(a + (size_t)(m0 + srow) * DIMK + k0 + scol, (short*)Al + (w * 64) * 8);
        gload16(a + (size_t)(m0 + srow1) * DIMK + k0 + scol1, (short*)Al + (256 + w * 64) * 8);
        gload16(b + (size_t)(n0 + srow) * DIMK + k0 + scol, (short*)Bl + (w * 64) * 8);
        gload16(b + (size_t)(n0 + srow1) * DIMK + k0 + scol1, (short*)Bl + (256 + w * 64) * 8);
        __syncthreads();
        bf16x8 af[4], bfr[4];
        for (int mt = 0; mt < 4; mt++)
            af[mt] = *reinterpret_cast<const bf16x8*>(&Al[wm + mt * 16 + lo][hi * 8]);
        for (int nt = 0; nt < 4; nt++)
            bfr[nt] = *reinterpret_cast<const bf16x8*>(&Bl[wn + nt * 16 + lo][hi * 8]);
        for (int mt = 0; mt < 4; mt++)
            for (int nt = 0; nt < 4; nt++)
                acc[mt][nt] = __builtin_amdgcn_mfma_f32_16x16x32_bf16(af[mt], bfr[nt],
                                                                      acc[mt][nt], 0, 0, 0);
        __syncthreads();
    }

    for (int mt = 0; mt < 4; mt++) {
        int trow = m0 + wm + mt * 16 + hi * 4;
        for (int nt = 0; nt < 4; nt++) {
            int e = n0 + wn + nt * 16 + lo;
            for (int r = 0; r < 4; r++)
                out[(size_t)(trow + r) * 1024 + e] = acc[mt][nt][r];
        }
    }
}

extern "C" void kernel_launch(void* const* d_in, const int* in_sizes, int n_in,
                              void* d_out, int out_size, void* d_ws, size_t ws_size,
                              hipStream_t stream) {
    const float* x = (const float*)d_in[0];
    const float* wqkv = (const float*)d_in[1];
    const float* wout = (const float*)d_in[2];
    float* out = (float*)d_out;

    char* ws = (char*)d_ws;
    short* xb  = (short*)(ws);                       // 8 MB  [4096][1024]
    short* wqb = (short*)(ws + 8388608);             // 6 MB  [3072][1024]
    short* wob = (short*)(ws + 8388608 + 6291456);   // 2 MB  [1024][1024]
    short* qq  = (short*)(ws + 16777216);            // 8 MB  [32][2048][64]
    short* kk  = (short*)(ws + 25165824);            // 8 MB  [32][2048][64]
    short* vt  = (short*)(ws + 33554432);            // 8 MB  [32][64][2048]
    short* ao  = xb;                                 // reuse xb region after GEMM1

    hipLaunchKernelGGL(cast_kernel, dim3(4096), dim3(256), 0, stream, x, xb, 1048576);
    hipLaunchKernelGGL(cast_kernel, dim3(3072), dim3(256), 0, stream, wqkv, wqb, 786432);
    hipLaunchKernelGGL(cast_kernel, dim3(1024), dim3(256), 0, stream, wqkv ? wout : wout, wob, 262144);
    hipLaunchKernelGGL(gemm_qkv, dim3(32, 24), dim3(256), 0, stream, xb, wqb, qq, kk, vt);
    hipLaunchKernelGGL(attn_kernel, dim3(32, 32), dim3(256), 0, stream, qq, kk, vt, ao);
    hipLaunchKernelGGL(gemm_out, dim3(32, 8), dim3(256), 0, stream, ao, wob, out);
}